// Round 5
// baseline (664.357 us; speedup 1.0000x reference)
//
#include <hip/hip_runtime.h>
#include <hip/hip_bf16.h>
#include <math.h>

#define N_NODES 20000
#define F 128
#define NRBF 20
#define E_EDGES 320000
#define F3 (3 * F)   // 384
#define NCHUNK ((N_NODES + 255) / 256)   // 79

__device__ __forceinline__ float silu_f(float x) {
    return x / (1.0f + __expf(-x));
}

// bf16 pack/unpack helpers (bf16 bits live in the upper 16 of the fp32 pattern)
__device__ __forceinline__ unsigned short f2bf(float x) {
    __hip_bfloat16 h = __float2bfloat16(x);
    return *(unsigned short*)&h;
}
__device__ __forceinline__ unsigned pack2(float a, float b) {
    return (unsigned)f2bf(a) | ((unsigned)f2bf(b) << 16);
}
__device__ __forceinline__ float bf_lo(unsigned u) { return __uint_as_float(u << 16); }
__device__ __forceinline__ float bf_hi(unsigned u) { return __uint_as_float(u & 0xffff0000u); }

// ---------------------------------------------------------------------------
// Kernel A: per-node MLP -> packed bf16 filter plane.
//   h_pack[n*F+f] = uint2{ pack(hs, hvs), pack(hvv, 0) }
// ---------------------------------------------------------------------------
#define NTILE_A 8
__global__ __launch_bounds__(128) void node_mlp_kernel(
    const float* __restrict__ s, const float* __restrict__ W1, const float* __restrict__ b1,
    const float* __restrict__ W2, const float* __restrict__ b2,
    uint2* __restrict__ h_pack)
{
    __shared__ float sl[NTILE_A][F];
    __shared__ float hid[NTILE_A][F];
    const int g = threadIdx.x;
    const int n0 = blockIdx.x * NTILE_A;

    #pragma unroll
    for (int t = 0; t < NTILE_A; ++t)
        sl[t][g] = s[(size_t)(n0 + t) * F + g];
    __syncthreads();

    float acc[NTILE_A];
    #pragma unroll
    for (int t = 0; t < NTILE_A; ++t) acc[t] = 0.0f;
    for (int f = 0; f < F; f += 4) {
        float w0 = W1[(f + 0) * F + g];
        float w1 = W1[(f + 1) * F + g];
        float w2 = W1[(f + 2) * F + g];
        float w3 = W1[(f + 3) * F + g];
        #pragma unroll
        for (int t = 0; t < NTILE_A; ++t) {
            float4 sv = *(const float4*)&sl[t][f];
            acc[t] += sv.x * w0 + sv.y * w1 + sv.z * w2 + sv.w * w3;
        }
    }
    float bb = b1[g];
    #pragma unroll
    for (int t = 0; t < NTILE_A; ++t) hid[t][g] = silu_f(acc[t] + bb);
    __syncthreads();

    float a0[NTILE_A], a1[NTILE_A], a2[NTILE_A];
    #pragma unroll
    for (int t = 0; t < NTILE_A; ++t) { a0[t] = 0.0f; a1[t] = 0.0f; a2[t] = 0.0f; }

    for (int k = 0; k < F; k += 4) {
        float wA[4], wB[4], wC[4];
        #pragma unroll
        for (int kk = 0; kk < 4; ++kk) {
            wA[kk] = W2[(k + kk) * F3 + g];
            wB[kk] = W2[(k + kk) * F3 + F + g];
            wC[kk] = W2[(k + kk) * F3 + 2 * F + g];
        }
        #pragma unroll
        for (int t = 0; t < NTILE_A; ++t) {
            float4 hv = *(const float4*)&hid[t][k];
            a0[t] += hv.x * wA[0] + hv.y * wA[1] + hv.z * wA[2] + hv.w * wA[3];
            a1[t] += hv.x * wB[0] + hv.y * wB[1] + hv.z * wB[2] + hv.w * wB[3];
            a2[t] += hv.x * wC[0] + hv.y * wC[1] + hv.z * wC[2] + hv.w * wC[3];
        }
    }
    const float bs = b2[g], bvs = b2[F + g], bvv = b2[2 * F + g];
    #pragma unroll
    for (int t = 0; t < NTILE_A; ++t) {
        h_pack[(size_t)(n0 + t) * F + g] =
            make_uint2(pack2(a0[t] + bs, a1[t] + bvs), pack2(a2[t] + bvv, 0.0f));
    }
}

// ---------------------------------------------------------------------------
// cast v -> packed bf16: v_pack[n*F+f] = uint2{ pack(v0,v1), pack(v2,0) }
// ---------------------------------------------------------------------------
__global__ __launch_bounds__(256) void cast_v_kernel(const float* __restrict__ v,
                                                     uint2* __restrict__ v_pack)
{
    int tid = blockIdx.x * 256 + threadIdx.x;
    if (tid >= N_NODES * F) return;
    int n = tid >> 7;
    int f = tid & 127;
    const float* vp = v + (size_t)n * F3 + f * 3;
    v_pack[tid] = make_uint2(pack2(vp[0], vp[1]), pack2(vp[2], 0.0f));
}

// ---------------------------------------------------------------------------
// CSR build: histogram -> 3-phase scan -> scatter
// ---------------------------------------------------------------------------
__global__ __launch_bounds__(256) void hist_kernel(const int* __restrict__ i_index,
                                                   int* __restrict__ counts)
{
    int e = blockIdx.x * 256 + threadIdx.x;
    if (e < E_EDGES) atomicAdd(&counts[i_index[e]], 1);
}

__global__ __launch_bounds__(256) void scan_p1(const int* __restrict__ counts,
                                               int* __restrict__ row_start,
                                               int* __restrict__ chunk_sum)
{
    __shared__ int buf[256];
    const int tid = threadIdx.x;
    const int idx = blockIdx.x * 256 + tid;
    int val = (idx < N_NODES) ? counts[idx] : 0;
    buf[tid] = val;
    __syncthreads();
    for (int off = 1; off < 256; off <<= 1) {
        int t = (tid >= off) ? buf[tid - off] : 0;
        __syncthreads();
        buf[tid] += t;
        __syncthreads();
    }
    if (idx < N_NODES) row_start[idx] = buf[tid] - val;
    if (tid == 255) chunk_sum[blockIdx.x] = buf[255];
}

__global__ __launch_bounds__(128) void scan_p2(const int* __restrict__ chunk_sum,
                                               int* __restrict__ chunk_off)
{
    __shared__ int buf[128];
    const int tid = threadIdx.x;
    int val = (tid < NCHUNK) ? chunk_sum[tid] : 0;
    buf[tid] = val;
    __syncthreads();
    for (int off = 1; off < 128; off <<= 1) {
        int t = (tid >= off) ? buf[tid - off] : 0;
        __syncthreads();
        buf[tid] += t;
        __syncthreads();
    }
    if (tid < NCHUNK) chunk_off[tid] = buf[tid] - val;
}

__global__ __launch_bounds__(256) void scan_p3(int* __restrict__ row_start,
                                               const int* __restrict__ chunk_off,
                                               int* __restrict__ cursor)
{
    int idx = blockIdx.x * 256 + threadIdx.x;
    if (idx < N_NODES) {
        int vv = row_start[idx] + chunk_off[blockIdx.x];
        row_start[idx] = vv;
        cursor[idx] = vv;
    }
    if (idx == 0) row_start[N_NODES] = E_EDGES;
}

__global__ __launch_bounds__(256) void scatter_kernel(const int* __restrict__ i_index,
                                                      int* __restrict__ cursor,
                                                      int* __restrict__ edge_ids)
{
    int e = blockIdx.x * 256 + threadIdx.x;
    if (e < E_EDGES) {
        int pos = atomicAdd(&cursor[i_index[e]], 1);
        edge_ids[pos] = e;
    }
}

// ---------------------------------------------------------------------------
// Kernel B: per-destination-node aggregation. Packed bf16 gathers (2×8B/edge),
// float4 rbf loads, edge loop unrolled x2 for MLP. No scalarization.
// Outputs straight into d_out: s_agg [n][f], v_agg d-major [n][d][f].
// ---------------------------------------------------------------------------
struct EdgeAcc { float s, v0, v1, v2; };

__device__ __forceinline__ void edge_body(
    int e, int j, int f,
    const float* __restrict__ rbf, const float* __restrict__ dir,
    const uint2* __restrict__ h_pack, const uint2* __restrict__ v_pack,
    const float* wr0, const float* wr1, const float* wr2,
    float br0, float br1, float br2, EdgeAcc& a)
{
    const float cc = 0.6283185307179586f;   // pi/5
    float x0 = br0, x1 = br1, x2 = br2;
    #pragma unroll
    for (int k4 = 0; k4 < NRBF; k4 += 4) {
        float4 r = *(const float4*)&rbf[(size_t)e * NRBF + k4];
        x0 += r.x * wr0[k4] + r.y * wr0[k4 + 1] + r.z * wr0[k4 + 2] + r.w * wr0[k4 + 3];
        x1 += r.x * wr1[k4] + r.y * wr1[k4 + 1] + r.z * wr1[k4 + 2] + r.w * wr1[k4 + 3];
        x2 += r.x * wr2[k4] + r.y * wr2[k4 + 1] + r.z * wr2[k4 + 2] + r.w * wr2[k4 + 3];
    }
    float w0 = (x0 < 5.0f) ? 0.5f * (__cosf(x0 * cc) + 1.0f) : 0.0f;
    float w1 = (x1 < 5.0f) ? 0.5f * (__cosf(x1 * cc) + 1.0f) : 0.0f;
    float w2 = (x2 < 5.0f) ? 0.5f * (__cosf(x2 * cc) + 1.0f) : 0.0f;

    uint2 hp = h_pack[(size_t)j * F + f];
    float hs  = bf_lo(hp.x) * w0;
    float hvs = bf_hi(hp.x) * w1;
    float hvv = bf_lo(hp.y) * w2;

    float dx = dir[(size_t)e * 3 + 0];
    float dy = dir[(size_t)e * 3 + 1];
    float dz = dir[(size_t)e * 3 + 2];

    uint2 vp = v_pack[(size_t)j * F + f];

    a.s  += hs;
    a.v0 += hvs * dx + hvv * bf_lo(vp.x);
    a.v1 += hvs * dy + hvv * bf_hi(vp.x);
    a.v2 += hvs * dz + hvv * bf_lo(vp.y);
}

__global__ __launch_bounds__(128) void agg_kernel(
    const float* __restrict__ s, const float* __restrict__ v,
    const float* __restrict__ rbf, const float* __restrict__ dir,
    const int* __restrict__ j_index,
    const float* __restrict__ Wr, const float* __restrict__ br,
    const uint2* __restrict__ h_pack, const uint2* __restrict__ v_pack,
    const int* __restrict__ row_start, const int* __restrict__ edge_ids,
    float* __restrict__ s_agg, float* __restrict__ v_agg)
{
    const int f = threadIdx.x;
    const int n = blockIdx.x;

    float wr0[NRBF], wr1[NRBF], wr2[NRBF];
    #pragma unroll
    for (int k = 0; k < NRBF; ++k) {
        wr0[k] = Wr[k * F3 + f];
        wr1[k] = Wr[k * F3 + F + f];
        wr2[k] = Wr[k * F3 + 2 * F + f];
    }
    const float br0 = br[f], br1 = br[F + f], br2 = br[2 * F + f];

    EdgeAcc a;
    a.s  = s[(size_t)n * F + f];
    a.v0 = v[(size_t)n * F3 + f * 3 + 0];
    a.v1 = v[(size_t)n * F3 + f * 3 + 1];
    a.v2 = v[(size_t)n * F3 + f * 3 + 2];

    const int beg = row_start[n];
    const int end = row_start[n + 1];

    int idx = beg;
    for (; idx + 2 <= end; idx += 2) {
        int e0 = edge_ids[idx];
        int e1 = edge_ids[idx + 1];
        int j0 = j_index[e0];
        int j1 = j_index[e1];
        edge_body(e0, j0, f, rbf, dir, h_pack, v_pack, wr0, wr1, wr2, br0, br1, br2, a);
        edge_body(e1, j1, f, rbf, dir, h_pack, v_pack, wr0, wr1, wr2, br0, br1, br2, a);
    }
    if (idx < end) {
        int e0 = edge_ids[idx];
        int j0 = j_index[e0];
        edge_body(e0, j0, f, rbf, dir, h_pack, v_pack, wr0, wr1, wr2, br0, br1, br2, a);
    }

    s_agg[(size_t)n * F + f] = a.s;
    v_agg[(size_t)n * F3 + 0 * F + f] = a.v0;   // d-major
    v_agg[(size_t)n * F3 + 1 * F + f] = a.v1;
    v_agg[(size_t)n * F3 + 2 * F + f] = a.v2;
}

// ---------------------------------------------------------------------------
// Kernel C: per-node update — T_C=4 with vectorized LDS reads (b64/b128).
// Reads s_agg/v_agg from d_out, rewrites same rows in place.
// ---------------------------------------------------------------------------
#define T_C 4
__global__ __launch_bounds__(128) void update_kernel(
    const float* __restrict__ s_agg, const float* __restrict__ v_agg,
    const float* __restrict__ WU, const float* __restrict__ bU,
    const float* __restrict__ WV, const float* __restrict__ bV,
    const float* __restrict__ M1, const float* __restrict__ bm1,
    const float* __restrict__ M2, const float* __restrict__ bm2,
    float* __restrict__ s_out, float* __restrict__ v_out)
{
    __shared__ float vl[T_C][3][F];     // d-major
    __shared__ float inl[T_C][2 * F];   // [Vv_norm, s]
    __shared__ float hidl[T_C][F];

    const int g = threadIdx.x;
    const int n0 = blockIdx.x * T_C;

    for (int idx = g; idx < T_C * F3; idx += 128)
        ((float*)vl)[idx] = v_agg[(size_t)n0 * F3 + idx];
    #pragma unroll
    for (int t = 0; t < T_C; ++t)
        inl[t][F + g] = s_agg[(size_t)(n0 + t) * F + g];
    __syncthreads();

    // Uv / Vv: f unrolled by 2, b64 LDS reads
    float uacc[T_C][3], vacc[T_C][3];
    #pragma unroll
    for (int t = 0; t < T_C; ++t)
        #pragma unroll
        for (int d = 0; d < 3; ++d) { uacc[t][d] = 0.0f; vacc[t][d] = 0.0f; }

    for (int f = 0; f < F; f += 2) {
        float wu0 = WU[(f + 0) * F + g], wu1 = WU[(f + 1) * F + g];
        float wv0 = WV[(f + 0) * F + g], wv1 = WV[(f + 1) * F + g];
        #pragma unroll
        for (int t = 0; t < T_C; ++t) {
            #pragma unroll
            for (int d = 0; d < 3; ++d) {
                float2 vv = *(const float2*)&vl[t][d][f];
                uacc[t][d] += vv.x * wu0 + vv.y * wu1;
                vacc[t][d] += vv.x * wv0 + vv.y * wv1;
            }
        }
    }
    float bu = bU[g], bv = bV[g];
    #pragma unroll
    for (int t = 0; t < T_C; ++t) {
        #pragma unroll
        for (int d = 0; d < 3; ++d) { uacc[t][d] += bu; vacc[t][d] += bv; }
        inl[t][g] = sqrtf(vacc[t][0] * vacc[t][0] + vacc[t][1] * vacc[t][1] +
                          vacc[t][2] * vacc[t][2]);
    }
    __syncthreads();

    // MLP stage 1: k unrolled by 4, b128 LDS reads
    float hacc[T_C];
    #pragma unroll
    for (int t = 0; t < T_C; ++t) hacc[t] = 0.0f;
    for (int k = 0; k < 2 * F; k += 4) {
        float m0 = M1[(k + 0) * F + g], m1 = M1[(k + 1) * F + g];
        float m2 = M1[(k + 2) * F + g], m3 = M1[(k + 3) * F + g];
        #pragma unroll
        for (int t = 0; t < T_C; ++t) {
            float4 iv = *(const float4*)&inl[t][k];
            hacc[t] += iv.x * m0 + iv.y * m1 + iv.z * m2 + iv.w * m3;
        }
    }
    float bh = bm1[g];
    #pragma unroll
    for (int t = 0; t < T_C; ++t) hidl[t][g] = silu_f(hacc[t] + bh);
    __syncthreads();

    // MLP stage 2: 3 outputs per thread, k unrolled by 2, b64 LDS reads
    float ma[T_C], mb[T_C], mc[T_C];
    #pragma unroll
    for (int t = 0; t < T_C; ++t) { ma[t] = 0.0f; mb[t] = 0.0f; mc[t] = 0.0f; }
    for (int k = 0; k < F; k += 2) {
        float wA0 = M2[(k + 0) * F3 + g],         wA1 = M2[(k + 1) * F3 + g];
        float wB0 = M2[(k + 0) * F3 + F + g],     wB1 = M2[(k + 1) * F3 + F + g];
        float wC0 = M2[(k + 0) * F3 + 2 * F + g], wC1 = M2[(k + 1) * F3 + 2 * F + g];
        #pragma unroll
        for (int t = 0; t < T_C; ++t) {
            float2 hv = *(const float2*)&hidl[t][k];
            ma[t] += hv.x * wA0 + hv.y * wA1;
            mb[t] += hv.x * wB0 + hv.y * wB1;
            mc[t] += hv.x * wC0 + hv.y * wC1;
        }
    }
    const float bvv = bm2[g], bsv = bm2[F + g], bss = bm2[2 * F + g];

    #pragma unroll
    for (int t = 0; t < T_C; ++t) {
        float a_vv = ma[t] + bvv;
        float a_sv = mb[t] + bsv;
        float a_ss = mc[t] + bss;
        float dotuv = uacc[t][0] * vacc[t][0] + uacc[t][1] * vacc[t][1] +
                      uacc[t][2] * vacc[t][2];
        s_out[(size_t)(n0 + t) * F + g] = inl[t][F + g] + dotuv * a_sv + a_ss;
        #pragma unroll
        for (int d = 0; d < 3; ++d)
            v_out[(size_t)(n0 + t) * F3 + g * 3 + d] = vl[t][d][g] + a_vv * uacc[t][d];
    }
}

// ---------------------------------------------------------------------------
extern "C" void kernel_launch(void* const* d_in, const int* in_sizes, int n_in,
                              void* d_out, int out_size, void* d_ws, size_t ws_size,
                              hipStream_t stream) {
    const float* s    = (const float*)d_in[0];
    const float* v    = (const float*)d_in[1];
    const float* rbf  = (const float*)d_in[2];
    const float* dir  = (const float*)d_in[3];
    const float* W1   = (const float*)d_in[4];
    const float* b1   = (const float*)d_in[5];
    const float* W2   = (const float*)d_in[6];
    const float* b2   = (const float*)d_in[7];
    const float* Wr   = (const float*)d_in[8];
    const float* br   = (const float*)d_in[9];
    const float* WU   = (const float*)d_in[10];
    const float* bU   = (const float*)d_in[11];
    const float* WV   = (const float*)d_in[12];
    const float* bV   = (const float*)d_in[13];
    const float* M1   = (const float*)d_in[14];
    const float* bm1  = (const float*)d_in[15];
    const float* M2   = (const float*)d_in[16];
    const float* bm2  = (const float*)d_in[17];
    const int* i_index = (const int*)d_in[18];
    const int* j_index = (const int*)d_in[19];

    float* out_s = (float*)d_out;                     // N*F ; doubles as s_agg
    float* out_v = out_s + (size_t)N_NODES * F;       // N*F*3 ; doubles as v_agg (d-major)

    // workspace
    char* w = (char*)d_ws;
    uint2* h_pack = (uint2*)w;   w += (size_t)N_NODES * F * 8;
    uint2* v_pack = (uint2*)w;   w += (size_t)N_NODES * F * 8;
    int* counts    = (int*)w;    w += (size_t)N_NODES * 4;
    int* row_start = (int*)w;    w += (size_t)(N_NODES + 1) * 4;
    int* cursor    = (int*)w;    w += (size_t)N_NODES * 4;
    int* edge_ids  = (int*)w;    w += (size_t)E_EDGES * 4;
    int* chunk_sum = (int*)w;    w += 128 * 4;
    int* chunk_off = (int*)w;

    hipMemsetAsync(counts, 0, sizeof(int) * N_NODES, stream);

    node_mlp_kernel<<<N_NODES / NTILE_A, 128, 0, stream>>>(s, W1, b1, W2, b2, h_pack);
    cast_v_kernel<<<(N_NODES * F + 255) / 256, 256, 0, stream>>>(v, v_pack);

    hist_kernel<<<(E_EDGES + 255) / 256, 256, 0, stream>>>(i_index, counts);
    scan_p1<<<NCHUNK, 256, 0, stream>>>(counts, row_start, chunk_sum);
    scan_p2<<<1, 128, 0, stream>>>(chunk_sum, chunk_off);
    scan_p3<<<NCHUNK, 256, 0, stream>>>(row_start, chunk_off, cursor);
    scatter_kernel<<<(E_EDGES + 255) / 256, 256, 0, stream>>>(i_index, cursor, edge_ids);

    agg_kernel<<<N_NODES, 128, 0, stream>>>(s, v, rbf, dir, j_index, Wr, br,
                                            h_pack, v_pack, row_start, edge_ids,
                                            out_s, out_v);

    update_kernel<<<N_NODES / T_C, 128, 0, stream>>>(out_s, out_v, WU, bU, WV, bV,
                                                     M1, bm1, M2, bm2, out_s, out_v);
}

// Round 6
// 529.028 us; speedup vs baseline: 1.2558x; 1.2558x over previous
//
#include <hip/hip_runtime.h>
#include <math.h>

#define N_NODES 20000
#define F 128
#define NRBF 20
#define E_EDGES 320000
#define F3 (3 * F)   // 384
#define NCHUNK ((N_NODES + 255) / 256)   // 79

__device__ __forceinline__ float silu_f(float x) {
    return x / (1.0f + __expf(-x));
}

// ---------------------------------------------------------------------------
// Kernel A: per-node MLP  h[n,o] = silu(s[n]@W1 + b1) @ W2 + b2   (o in [0,384))
// (exact R2 version — best measured)
// ---------------------------------------------------------------------------
#define NTILE_A 8
__global__ __launch_bounds__(128) void node_mlp_kernel(
    const float* __restrict__ s, const float* __restrict__ W1, const float* __restrict__ b1,
    const float* __restrict__ W2, const float* __restrict__ b2, float* __restrict__ h)
{
    __shared__ float sl[NTILE_A][F];
    __shared__ float hid[NTILE_A][F];
    const int g = threadIdx.x;
    const int n0 = blockIdx.x * NTILE_A;

    #pragma unroll
    for (int t = 0; t < NTILE_A; ++t)
        sl[t][g] = s[(size_t)(n0 + t) * F + g];
    __syncthreads();

    float acc[NTILE_A];
    #pragma unroll
    for (int t = 0; t < NTILE_A; ++t) acc[t] = 0.0f;
    for (int f = 0; f < F; ++f) {
        float w = W1[f * F + g];
        #pragma unroll
        for (int t = 0; t < NTILE_A; ++t) acc[t] += sl[t][f] * w;
    }
    float bb = b1[g];
    #pragma unroll
    for (int t = 0; t < NTILE_A; ++t) hid[t][g] = silu_f(acc[t] + bb);
    __syncthreads();

    float acc2[3][NTILE_A];
    #pragma unroll
    for (int o3 = 0; o3 < 3; ++o3)
        #pragma unroll
        for (int t = 0; t < NTILE_A; ++t) acc2[o3][t] = 0.0f;

    for (int k = 0; k < F; ++k) {
        #pragma unroll
        for (int o3 = 0; o3 < 3; ++o3) {
            float w2 = W2[k * F3 + o3 * F + g];
            #pragma unroll
            for (int t = 0; t < NTILE_A; ++t) acc2[o3][t] += hid[t][k] * w2;
        }
    }
    #pragma unroll
    for (int o3 = 0; o3 < 3; ++o3) {
        float bv = b2[o3 * F + g];
        #pragma unroll
        for (int t = 0; t < NTILE_A; ++t)
            h[(size_t)(n0 + t) * F3 + o3 * F + g] = acc2[o3][t] + bv;
    }
}

// ---------------------------------------------------------------------------
// CSR build: histogram -> 3-phase parallel scan -> scatter
// ---------------------------------------------------------------------------
__global__ __launch_bounds__(256) void hist_kernel(const int* __restrict__ i_index,
                                                   int* __restrict__ counts)
{
    int e = blockIdx.x * 256 + threadIdx.x;
    if (e < E_EDGES) atomicAdd(&counts[i_index[e]], 1);
}

__global__ __launch_bounds__(256) void scan_p1(const int* __restrict__ counts,
                                               int* __restrict__ row_start,
                                               int* __restrict__ chunk_sum)
{
    __shared__ int buf[256];
    const int tid = threadIdx.x;
    const int idx = blockIdx.x * 256 + tid;
    int val = (idx < N_NODES) ? counts[idx] : 0;
    buf[tid] = val;
    __syncthreads();
    for (int off = 1; off < 256; off <<= 1) {
        int t = (tid >= off) ? buf[tid - off] : 0;
        __syncthreads();
        buf[tid] += t;
        __syncthreads();
    }
    if (idx < N_NODES) row_start[idx] = buf[tid] - val;
    if (tid == 255) chunk_sum[blockIdx.x] = buf[255];
}

__global__ __launch_bounds__(128) void scan_p2(const int* __restrict__ chunk_sum,
                                               int* __restrict__ chunk_off)
{
    __shared__ int buf[128];
    const int tid = threadIdx.x;
    int val = (tid < NCHUNK) ? chunk_sum[tid] : 0;
    buf[tid] = val;
    __syncthreads();
    for (int off = 1; off < 128; off <<= 1) {
        int t = (tid >= off) ? buf[tid - off] : 0;
        __syncthreads();
        buf[tid] += t;
        __syncthreads();
    }
    if (tid < NCHUNK) chunk_off[tid] = buf[tid] - val;
}

__global__ __launch_bounds__(256) void scan_p3(int* __restrict__ row_start,
                                               const int* __restrict__ chunk_off,
                                               int* __restrict__ cursor)
{
    int idx = blockIdx.x * 256 + threadIdx.x;
    if (idx < N_NODES) {
        int vv = row_start[idx] + chunk_off[blockIdx.x];
        row_start[idx] = vv;
        cursor[idx] = vv;
    }
    if (idx == 0) row_start[N_NODES] = E_EDGES;
}

__global__ __launch_bounds__(256) void scatter_kernel(const int* __restrict__ i_index,
                                                      int* __restrict__ cursor,
                                                      int* __restrict__ edge_ids)
{
    int e = blockIdx.x * 256 + threadIdx.x;
    if (e < E_EDGES) {
        int pos = atomicAdd(&cursor[i_index[e]], 1);
        edge_ids[pos] = e;
    }
}

// ---------------------------------------------------------------------------
// Kernel B: per-destination-node aggregation (exact R2 version — best measured:
// fp32 gathers, five independent loads/edge, no scalarization, no unroll).
// ---------------------------------------------------------------------------
__global__ __launch_bounds__(128) void agg_kernel(
    const float* __restrict__ s, const float* __restrict__ v,
    const float* __restrict__ rbf, const float* __restrict__ dir,
    const int* __restrict__ j_index,
    const float* __restrict__ Wr, const float* __restrict__ br,
    const float* __restrict__ h,
    const int* __restrict__ row_start, const int* __restrict__ edge_ids,
    float* __restrict__ s_agg, float* __restrict__ v_agg)
{
    const int f = threadIdx.x;
    const int n = blockIdx.x;

    float wr0[NRBF], wr1[NRBF], wr2[NRBF];
    #pragma unroll
    for (int k = 0; k < NRBF; ++k) {
        wr0[k] = Wr[k * F3 + f];
        wr1[k] = Wr[k * F3 + F + f];
        wr2[k] = Wr[k * F3 + 2 * F + f];
    }
    const float br0 = br[f], br1 = br[F + f], br2 = br[2 * F + f];

    float s_acc = s[(size_t)n * F + f];
    float v0 = v[(size_t)n * F3 + f * 3 + 0];
    float v1 = v[(size_t)n * F3 + f * 3 + 1];
    float v2 = v[(size_t)n * F3 + f * 3 + 2];

    const int beg = row_start[n];
    const int end = row_start[n + 1];
    const float cc = 0.6283185307179586f;   // pi/5

    for (int idx = beg; idx < end; ++idx) {
        const int e = edge_ids[idx];
        const int j = j_index[e];

        float x0 = br0, x1 = br1, x2 = br2;
        #pragma unroll
        for (int k = 0; k < NRBF; ++k) {
            float r = rbf[(size_t)e * NRBF + k];
            x0 += r * wr0[k];
            x1 += r * wr1[k];
            x2 += r * wr2[k];
        }
        float w0 = (x0 < 5.0f) ? 0.5f * (__cosf(x0 * cc) + 1.0f) : 0.0f;
        float w1 = (x1 < 5.0f) ? 0.5f * (__cosf(x1 * cc) + 1.0f) : 0.0f;
        float w2 = (x2 < 5.0f) ? 0.5f * (__cosf(x2 * cc) + 1.0f) : 0.0f;

        float hs  = h[(size_t)j * F3 + f]         * w0;
        float hvs = h[(size_t)j * F3 + F + f]     * w1;
        float hvv = h[(size_t)j * F3 + 2 * F + f] * w2;

        float dx = dir[(size_t)e * 3 + 0];
        float dy = dir[(size_t)e * 3 + 1];
        float dz = dir[(size_t)e * 3 + 2];

        float vj0 = v[(size_t)j * F3 + f * 3 + 0];
        float vj1 = v[(size_t)j * F3 + f * 3 + 1];
        float vj2 = v[(size_t)j * F3 + f * 3 + 2];

        s_acc += hs;
        v0 += hvs * dx + hvv * vj0;
        v1 += hvs * dy + hvv * vj1;
        v2 += hvs * dz + hvv * vj2;
    }

    s_agg[(size_t)n * F + f] = s_acc;
    v_agg[(size_t)n * F3 + f * 3 + 0] = v0;
    v_agg[(size_t)n * F3 + f * 3 + 1] = v1;
    v_agg[(size_t)n * F3 + f * 3 + 2] = v2;
}

// ---------------------------------------------------------------------------
// Kernel C: per-node update (exact R2 version — best measured: T_C=4,
// scalar wave-uniform LDS reads, f-major vl).
// ---------------------------------------------------------------------------
#define T_C 4
__global__ __launch_bounds__(128) void update_kernel(
    const float* __restrict__ s_agg, const float* __restrict__ v_agg,
    const float* __restrict__ WU, const float* __restrict__ bU,
    const float* __restrict__ WV, const float* __restrict__ bV,
    const float* __restrict__ M1, const float* __restrict__ bm1,
    const float* __restrict__ M2, const float* __restrict__ bm2,
    float* __restrict__ s_out, float* __restrict__ v_out)
{
    __shared__ float vl[T_C][F][3];
    __shared__ float inl[T_C][2 * F];
    __shared__ float hidl[T_C][F];

    const int g = threadIdx.x;
    const int n0 = blockIdx.x * T_C;

    for (int idx = g; idx < T_C * F3; idx += 128)
        ((float*)vl)[idx] = v_agg[(size_t)n0 * F3 + idx];
    #pragma unroll
    for (int t = 0; t < T_C; ++t)
        inl[t][F + g] = s_agg[(size_t)(n0 + t) * F + g];
    __syncthreads();

    float uacc[T_C][3], vacc[T_C][3];
    #pragma unroll
    for (int t = 0; t < T_C; ++t)
        #pragma unroll
        for (int d = 0; d < 3; ++d) { uacc[t][d] = 0.0f; vacc[t][d] = 0.0f; }

    for (int f = 0; f < F; ++f) {
        float wu = WU[f * F + g];
        float wv = WV[f * F + g];
        #pragma unroll
        for (int t = 0; t < T_C; ++t) {
            #pragma unroll
            for (int d = 0; d < 3; ++d) {
                float vv = vl[t][f][d];
                uacc[t][d] += vv * wu;
                vacc[t][d] += vv * wv;
            }
        }
    }
    float bu = bU[g], bv = bV[g];
    #pragma unroll
    for (int t = 0; t < T_C; ++t) {
        #pragma unroll
        for (int d = 0; d < 3; ++d) { uacc[t][d] += bu; vacc[t][d] += bv; }
        inl[t][g] = sqrtf(vacc[t][0] * vacc[t][0] + vacc[t][1] * vacc[t][1] +
                          vacc[t][2] * vacc[t][2]);
    }
    __syncthreads();

    float hacc[T_C];
    #pragma unroll
    for (int t = 0; t < T_C; ++t) hacc[t] = 0.0f;
    for (int k = 0; k < 2 * F; ++k) {
        float m1 = M1[k * F + g];
        #pragma unroll
        for (int t = 0; t < T_C; ++t) hacc[t] += inl[t][k] * m1;
    }
    float bh = bm1[g];
    #pragma unroll
    for (int t = 0; t < T_C; ++t) hidl[t][g] = silu_f(hacc[t] + bh);
    __syncthreads();

    float macc[3][T_C];
    #pragma unroll
    for (int o3 = 0; o3 < 3; ++o3)
        #pragma unroll
        for (int t = 0; t < T_C; ++t) macc[o3][t] = 0.0f;
    for (int k = 0; k < F; ++k) {
        #pragma unroll
        for (int o3 = 0; o3 < 3; ++o3) {
            float m2 = M2[k * F3 + o3 * F + g];
            #pragma unroll
            for (int t = 0; t < T_C; ++t) macc[o3][t] += hidl[t][k] * m2;
        }
    }
    const float bvv = bm2[g], bsv = bm2[F + g], bss = bm2[2 * F + g];

    #pragma unroll
    for (int t = 0; t < T_C; ++t) {
        float a_vv = macc[0][t] + bvv;
        float a_sv = macc[1][t] + bsv;
        float a_ss = macc[2][t] + bss;
        float dotuv = uacc[t][0] * vacc[t][0] + uacc[t][1] * vacc[t][1] +
                      uacc[t][2] * vacc[t][2];
        s_out[(size_t)(n0 + t) * F + g] = inl[t][F + g] + dotuv * a_sv + a_ss;
        #pragma unroll
        for (int d = 0; d < 3; ++d)
            v_out[(size_t)(n0 + t) * F3 + g * 3 + d] = vl[t][g][d] + a_vv * uacc[t][d];
    }
}

// ---------------------------------------------------------------------------
extern "C" void kernel_launch(void* const* d_in, const int* in_sizes, int n_in,
                              void* d_out, int out_size, void* d_ws, size_t ws_size,
                              hipStream_t stream) {
    const float* s    = (const float*)d_in[0];
    const float* v    = (const float*)d_in[1];
    const float* rbf  = (const float*)d_in[2];
    const float* dir  = (const float*)d_in[3];
    const float* W1   = (const float*)d_in[4];
    const float* b1   = (const float*)d_in[5];
    const float* W2   = (const float*)d_in[6];
    const float* b2   = (const float*)d_in[7];
    const float* Wr   = (const float*)d_in[8];
    const float* br   = (const float*)d_in[9];
    const float* WU   = (const float*)d_in[10];
    const float* bU   = (const float*)d_in[11];
    const float* WV   = (const float*)d_in[12];
    const float* bV   = (const float*)d_in[13];
    const float* M1   = (const float*)d_in[14];
    const float* bm1  = (const float*)d_in[15];
    const float* M2   = (const float*)d_in[16];
    const float* bm2  = (const float*)d_in[17];
    const int* i_index = (const int*)d_in[18];
    const int* j_index = (const int*)d_in[19];

    float* out_s = (float*)d_out;                     // N*F
    float* out_v = out_s + (size_t)N_NODES * F;       // N*F*3

    // workspace layout
    float* h       = (float*)d_ws;                         // N*384 floats
    float* s_agg   = h + (size_t)N_NODES * F3;             // N*128
    float* v_agg   = s_agg + (size_t)N_NODES * F;          // N*384
    int*   counts  = (int*)(v_agg + (size_t)N_NODES * F3); // N
    int*   row_start = counts + N_NODES;                   // N+1
    int*   cursor  = row_start + N_NODES + 1;              // N
    int*   edge_ids = cursor + N_NODES;                    // E
    int*   chunk_sum = edge_ids + E_EDGES;                 // 128
    int*   chunk_off = chunk_sum + 128;                    // 128

    hipMemsetAsync(counts, 0, sizeof(int) * N_NODES, stream);

    node_mlp_kernel<<<N_NODES / NTILE_A, 128, 0, stream>>>(s, W1, b1, W2, b2, h);

    hist_kernel<<<(E_EDGES + 255) / 256, 256, 0, stream>>>(i_index, counts);
    scan_p1<<<NCHUNK, 256, 0, stream>>>(counts, row_start, chunk_sum);
    scan_p2<<<1, 128, 0, stream>>>(chunk_sum, chunk_off);
    scan_p3<<<NCHUNK, 256, 0, stream>>>(row_start, chunk_off, cursor);
    scatter_kernel<<<(E_EDGES + 255) / 256, 256, 0, stream>>>(i_index, cursor, edge_ids);

    agg_kernel<<<N_NODES, 128, 0, stream>>>(s, v, rbf, dir, j_index, Wr, br, h,
                                            row_start, edge_ids, s_agg, v_agg);

    update_kernel<<<N_NODES / T_C, 128, 0, stream>>>(s_agg, v_agg, WU, bU, WV, bV,
                                                     M1, bm1, M2, bm2, out_s, out_v);
}

// Round 7
// 512.689 us; speedup vs baseline: 1.2958x; 1.0319x over previous
//
#include <hip/hip_runtime.h>
#include <hip/hip_bf16.h>
#include <math.h>

#define N_NODES 20000
#define F 128
#define NRBF 20
#define E_EDGES 320000
#define F3 (3 * F)   // 384
#define NCHUNK ((N_NODES + 255) / 256)   // 79

typedef __attribute__((ext_vector_type(8))) short bf16x8;
typedef __attribute__((ext_vector_type(4))) float f32x4;

__device__ __forceinline__ float silu_f(float x) {
    return x / (1.0f + __expf(-x));
}
__device__ __forceinline__ unsigned short bf_bits(float x) {
    __hip_bfloat16 b = __float2bfloat16(x);
    return *(unsigned short*)&b;
}

// ---------------------------------------------------------------------------
// Weight pre-swizzle into MFMA B-fragment order.
//   W1s[ct(8)][kc(4)][lane(64)][j(8)] ; W2s[ct(24)][kc(4)][lane(64)][j(8)]
//   element(lane,j) = W[k = kc*32 + (lane>>4)*8 + j][n = ct*16 + (lane&15)]
// ---------------------------------------------------------------------------
__global__ __launch_bounds__(256) void w_swizzle_kernel(
    const float* __restrict__ W1, const float* __restrict__ W2,
    unsigned short* __restrict__ W1s, unsigned short* __restrict__ W2s)
{
    int tid = blockIdx.x * 256 + threadIdx.x;   // one thread per (ct,kc,lane)
    if (tid < 8 * 4 * 64) {
        int lane = tid & 63, kc = (tid >> 6) & 3, ct = tid >> 8;
        int n = ct * 16 + (lane & 15);
        int k0 = kc * 32 + (lane >> 4) * 8;
        #pragma unroll
        for (int j = 0; j < 8; ++j)
            W1s[tid * 8 + j] = bf_bits(W1[(k0 + j) * F + n]);
    } else if (tid < 8 * 4 * 64 + 24 * 4 * 64) {
        int t = tid - 8 * 4 * 64;
        int lane = t & 63, kc = (t >> 6) & 3, ct = t >> 8;
        int n = ct * 16 + (lane & 15);
        int k0 = kc * 32 + (lane >> 4) * 8;
        #pragma unroll
        for (int j = 0; j < 8; ++j)
            W2s[t * 8 + j] = bf_bits(W2[(k0 + j) * F3 + n]);
    }
}

// ---------------------------------------------------------------------------
// Kernel A (MFMA): h = silu(s@W1+b1)@W2 + b2, bf16 inputs / fp32 accum.
// Block = 256 thr = 4 waves; 16 nodes per wave, 64 per block.
// ---------------------------------------------------------------------------
#define SLD 136   // padded row stride (elements) for LDS tiles
__global__ __launch_bounds__(256) void node_mlp_mfma(
    const float* __restrict__ s, const float* __restrict__ b1,
    const float* __restrict__ b2,
    const unsigned short* __restrict__ W1s, const unsigned short* __restrict__ W2s,
    float* __restrict__ h)
{
    __shared__ unsigned short Sl[64][SLD];        // 17408 B
    __shared__ unsigned short Hid[4][16][SLD];    // 17408 B

    const int tid = threadIdx.x;
    const int lane = tid & 63, wave = tid >> 6;
    const int m = lane & 15, quad = lane >> 4;
    const int n0 = blockIdx.x * 64;

    // stage S tile (bf16), coalesced; clamp OOB rows (stores are guarded later)
    for (int i = tid; i < 64 * F; i += 256) {
        int r = i >> 7, c = i & 127;
        int nn = n0 + r;
        if (nn >= N_NODES) nn = N_NODES - 1;
        Sl[r][c] = bf_bits(s[(size_t)nn * F + c]);
    }
    __syncthreads();

    // A fragments for GEMM1: A[m][k], m = lane&15, k = kc*32 + quad*8 + j
    const int arow = wave * 16 + m;
    bf16x8 a1[4];
    #pragma unroll
    for (int kc = 0; kc < 4; ++kc)
        a1[kc] = *(const bf16x8*)&Sl[arow][kc * 32 + quad * 8];

    // GEMM1 + bias + silu -> Hid (bf16 in LDS)
    const bf16x8* W1f = (const bf16x8*)W1s;
    #pragma unroll
    for (int ct = 0; ct < 8; ++ct) {
        f32x4 acc = {0.f, 0.f, 0.f, 0.f};
        #pragma unroll
        for (int kc = 0; kc < 4; ++kc)
            acc = __builtin_amdgcn_mfma_f32_16x16x32_bf16(
                a1[kc], W1f[(ct * 4 + kc) * 64 + lane], acc, 0, 0, 0);
        float bias = b1[ct * 16 + m];            // C col = lane&15
        #pragma unroll
        for (int r = 0; r < 4; ++r)              // C row = quad*4 + r
            Hid[wave][quad * 4 + r][ct * 16 + m] = bf_bits(silu_f(acc[r] + bias));
    }
    __syncthreads();

    // A fragments for GEMM2 from Hid
    bf16x8 a2[4];
    #pragma unroll
    for (int kc = 0; kc < 4; ++kc)
        a2[kc] = *(const bf16x8*)&Hid[wave][m][kc * 32 + quad * 8];

    // GEMM2 + bias -> h (fp32, layout [n][384] as before)
    const bf16x8* W2f = (const bf16x8*)W2s;
    #pragma unroll
    for (int ct = 0; ct < 24; ++ct) {
        f32x4 acc = {0.f, 0.f, 0.f, 0.f};
        #pragma unroll
        for (int kc = 0; kc < 4; ++kc)
            acc = __builtin_amdgcn_mfma_f32_16x16x32_bf16(
                a2[kc], W2f[(ct * 4 + kc) * 64 + lane], acc, 0, 0, 0);
        float bias = b2[ct * 16 + m];
        #pragma unroll
        for (int r = 0; r < 4; ++r) {
            int node = n0 + wave * 16 + quad * 4 + r;
            if (node < N_NODES)
                h[(size_t)node * F3 + ct * 16 + m] = acc[r] + bias;
        }
    }
}

// ---------------------------------------------------------------------------
// CSR build: histogram -> 3-phase parallel scan -> scatter (unchanged)
// ---------------------------------------------------------------------------
__global__ __launch_bounds__(256) void hist_kernel(const int* __restrict__ i_index,
                                                   int* __restrict__ counts)
{
    int e = blockIdx.x * 256 + threadIdx.x;
    if (e < E_EDGES) atomicAdd(&counts[i_index[e]], 1);
}

__global__ __launch_bounds__(256) void scan_p1(const int* __restrict__ counts,
                                               int* __restrict__ row_start,
                                               int* __restrict__ chunk_sum)
{
    __shared__ int buf[256];
    const int tid = threadIdx.x;
    const int idx = blockIdx.x * 256 + tid;
    int val = (idx < N_NODES) ? counts[idx] : 0;
    buf[tid] = val;
    __syncthreads();
    for (int off = 1; off < 256; off <<= 1) {
        int t = (tid >= off) ? buf[tid - off] : 0;
        __syncthreads();
        buf[tid] += t;
        __syncthreads();
    }
    if (idx < N_NODES) row_start[idx] = buf[tid] - val;
    if (tid == 255) chunk_sum[blockIdx.x] = buf[255];
}

__global__ __launch_bounds__(128) void scan_p2(const int* __restrict__ chunk_sum,
                                               int* __restrict__ chunk_off)
{
    __shared__ int buf[128];
    const int tid = threadIdx.x;
    int val = (tid < NCHUNK) ? chunk_sum[tid] : 0;
    buf[tid] = val;
    __syncthreads();
    for (int off = 1; off < 128; off <<= 1) {
        int t = (tid >= off) ? buf[tid - off] : 0;
        __syncthreads();
        buf[tid] += t;
        __syncthreads();
    }
    if (tid < NCHUNK) chunk_off[tid] = buf[tid] - val;
}

__global__ __launch_bounds__(256) void scan_p3(int* __restrict__ row_start,
                                               const int* __restrict__ chunk_off,
                                               int* __restrict__ cursor)
{
    int idx = blockIdx.x * 256 + threadIdx.x;
    if (idx < N_NODES) {
        int vv = row_start[idx] + chunk_off[blockIdx.x];
        row_start[idx] = vv;
        cursor[idx] = vv;
    }
    if (idx == 0) row_start[N_NODES] = E_EDGES;
}

__global__ __launch_bounds__(256) void scatter_kernel(const int* __restrict__ i_index,
                                                      int* __restrict__ cursor,
                                                      int* __restrict__ edge_ids)
{
    int e = blockIdx.x * 256 + threadIdx.x;
    if (e < E_EDGES) {
        int pos = atomicAdd(&cursor[i_index[e]], 1);
        edge_ids[pos] = e;
    }
}

// ---------------------------------------------------------------------------
// Kernel B: per-destination-node aggregation (unchanged R2/R6 version)
// ---------------------------------------------------------------------------
__global__ __launch_bounds__(128) void agg_kernel(
    const float* __restrict__ s, const float* __restrict__ v,
    const float* __restrict__ rbf, const float* __restrict__ dir,
    const int* __restrict__ j_index,
    const float* __restrict__ Wr, const float* __restrict__ br,
    const float* __restrict__ h,
    const int* __restrict__ row_start, const int* __restrict__ edge_ids,
    float* __restrict__ s_agg, float* __restrict__ v_agg)
{
    const int f = threadIdx.x;
    const int n = blockIdx.x;

    float wr0[NRBF], wr1[NRBF], wr2[NRBF];
    #pragma unroll
    for (int k = 0; k < NRBF; ++k) {
        wr0[k] = Wr[k * F3 + f];
        wr1[k] = Wr[k * F3 + F + f];
        wr2[k] = Wr[k * F3 + 2 * F + f];
    }
    const float br0 = br[f], br1 = br[F + f], br2 = br[2 * F + f];

    float s_acc = s[(size_t)n * F + f];
    float v0 = v[(size_t)n * F3 + f * 3 + 0];
    float v1 = v[(size_t)n * F3 + f * 3 + 1];
    float v2 = v[(size_t)n * F3 + f * 3 + 2];

    const int beg = row_start[n];
    const int end = row_start[n + 1];
    const float cc = 0.6283185307179586f;   // pi/5

    for (int idx = beg; idx < end; ++idx) {
        const int e = edge_ids[idx];
        const int j = j_index[e];

        float x0 = br0, x1 = br1, x2 = br2;
        #pragma unroll
        for (int k = 0; k < NRBF; ++k) {
            float r = rbf[(size_t)e * NRBF + k];
            x0 += r * wr0[k];
            x1 += r * wr1[k];
            x2 += r * wr2[k];
        }
        float w0 = (x0 < 5.0f) ? 0.5f * (__cosf(x0 * cc) + 1.0f) : 0.0f;
        float w1 = (x1 < 5.0f) ? 0.5f * (__cosf(x1 * cc) + 1.0f) : 0.0f;
        float w2 = (x2 < 5.0f) ? 0.5f * (__cosf(x2 * cc) + 1.0f) : 0.0f;

        float hs  = h[(size_t)j * F3 + f]         * w0;
        float hvs = h[(size_t)j * F3 + F + f]     * w1;
        float hvv = h[(size_t)j * F3 + 2 * F + f] * w2;

        float dx = dir[(size_t)e * 3 + 0];
        float dy = dir[(size_t)e * 3 + 1];
        float dz = dir[(size_t)e * 3 + 2];

        float vj0 = v[(size_t)j * F3 + f * 3 + 0];
        float vj1 = v[(size_t)j * F3 + f * 3 + 1];
        float vj2 = v[(size_t)j * F3 + f * 3 + 2];

        s_acc += hs;
        v0 += hvs * dx + hvv * vj0;
        v1 += hvs * dy + hvv * vj1;
        v2 += hvs * dz + hvv * vj2;
    }

    s_agg[(size_t)n * F + f] = s_acc;
    v_agg[(size_t)n * F3 + f * 3 + 0] = v0;
    v_agg[(size_t)n * F3 + f * 3 + 1] = v1;
    v_agg[(size_t)n * F3 + f * 3 + 2] = v2;
}

// ---------------------------------------------------------------------------
// Kernel C: per-node update (unchanged R2/R6 version)
// ---------------------------------------------------------------------------
#define T_C 4
__global__ __launch_bounds__(128) void update_kernel(
    const float* __restrict__ s_agg, const float* __restrict__ v_agg,
    const float* __restrict__ WU, const float* __restrict__ bU,
    const float* __restrict__ WV, const float* __restrict__ bV,
    const float* __restrict__ M1, const float* __restrict__ bm1,
    const float* __restrict__ M2, const float* __restrict__ bm2,
    float* __restrict__ s_out, float* __restrict__ v_out)
{
    __shared__ float vl[T_C][F][3];
    __shared__ float inl[T_C][2 * F];
    __shared__ float hidl[T_C][F];

    const int g = threadIdx.x;
    const int n0 = blockIdx.x * T_C;

    for (int idx = g; idx < T_C * F3; idx += 128)
        ((float*)vl)[idx] = v_agg[(size_t)n0 * F3 + idx];
    #pragma unroll
    for (int t = 0; t < T_C; ++t)
        inl[t][F + g] = s_agg[(size_t)(n0 + t) * F + g];
    __syncthreads();

    float uacc[T_C][3], vacc[T_C][3];
    #pragma unroll
    for (int t = 0; t < T_C; ++t)
        #pragma unroll
        for (int d = 0; d < 3; ++d) { uacc[t][d] = 0.0f; vacc[t][d] = 0.0f; }

    for (int f = 0; f < F; ++f) {
        float wu = WU[f * F + g];
        float wv = WV[f * F + g];
        #pragma unroll
        for (int t = 0; t < T_C; ++t) {
            #pragma unroll
            for (int d = 0; d < 3; ++d) {
                float vv = vl[t][f][d];
                uacc[t][d] += vv * wu;
                vacc[t][d] += vv * wv;
            }
        }
    }
    float bu = bU[g], bv = bV[g];
    #pragma unroll
    for (int t = 0; t < T_C; ++t) {
        #pragma unroll
        for (int d = 0; d < 3; ++d) { uacc[t][d] += bu; vacc[t][d] += bv; }
        inl[t][g] = sqrtf(vacc[t][0] * vacc[t][0] + vacc[t][1] * vacc[t][1] +
                          vacc[t][2] * vacc[t][2]);
    }
    __syncthreads();

    float hacc[T_C];
    #pragma unroll
    for (int t = 0; t < T_C; ++t) hacc[t] = 0.0f;
    for (int k = 0; k < 2 * F; ++k) {
        float m1 = M1[k * F + g];
        #pragma unroll
        for (int t = 0; t < T_C; ++t) hacc[t] += inl[t][k] * m1;
    }
    float bh = bm1[g];
    #pragma unroll
    for (int t = 0; t < T_C; ++t) hidl[t][g] = silu_f(hacc[t] + bh);
    __syncthreads();

    float macc[3][T_C];
    #pragma unroll
    for (int o3 = 0; o3 < 3; ++o3)
        #pragma unroll
        for (int t = 0; t < T_C; ++t) macc[o3][t] = 0.0f;
    for (int k = 0; k < F; ++k) {
        #pragma unroll
        for (int o3 = 0; o3 < 3; ++o3) {
            float m2 = M2[k * F3 + o3 * F + g];
            #pragma unroll
            for (int t = 0; t < T_C; ++t) macc[o3][t] += hidl[t][k] * m2;
        }
    }
    const float bvv = bm2[g], bsv = bm2[F + g], bss = bm2[2 * F + g];

    #pragma unroll
    for (int t = 0; t < T_C; ++t) {
        float a_vv = macc[0][t] + bvv;
        float a_sv = macc[1][t] + bsv;
        float a_ss = macc[2][t] + bss;
        float dotuv = uacc[t][0] * vacc[t][0] + uacc[t][1] * vacc[t][1] +
                      uacc[t][2] * vacc[t][2];
        s_out[(size_t)(n0 + t) * F + g] = inl[t][F + g] + dotuv * a_sv + a_ss;
        #pragma unroll
        for (int d = 0; d < 3; ++d)
            v_out[(size_t)(n0 + t) * F3 + g * 3 + d] = vl[t][g][d] + a_vv * uacc[t][d];
    }
}

// ---------------------------------------------------------------------------
extern "C" void kernel_launch(void* const* d_in, const int* in_sizes, int n_in,
                              void* d_out, int out_size, void* d_ws, size_t ws_size,
                              hipStream_t stream) {
    const float* s    = (const float*)d_in[0];
    const float* v    = (const float*)d_in[1];
    const float* rbf  = (const float*)d_in[2];
    const float* dir  = (const float*)d_in[3];
    const float* W1   = (const float*)d_in[4];
    const float* b1   = (const float*)d_in[5];
    const float* W2   = (const float*)d_in[6];
    const float* b2   = (const float*)d_in[7];
    const float* Wr   = (const float*)d_in[8];
    const float* br   = (const float*)d_in[9];
    const float* WU   = (const float*)d_in[10];
    const float* bU   = (const float*)d_in[11];
    const float* WV   = (const float*)d_in[12];
    const float* bV   = (const float*)d_in[13];
    const float* M1   = (const float*)d_in[14];
    const float* bm1  = (const float*)d_in[15];
    const float* M2   = (const float*)d_in[16];
    const float* bm2  = (const float*)d_in[17];
    const int* i_index = (const int*)d_in[18];
    const int* j_index = (const int*)d_in[19];

    float* out_s = (float*)d_out;                     // N*F
    float* out_v = out_s + (size_t)N_NODES * F;       // N*F*3

    // workspace layout
    float* h       = (float*)d_ws;                         // N*384 floats
    float* s_agg   = h + (size_t)N_NODES * F3;             // N*128
    float* v_agg   = s_agg + (size_t)N_NODES * F;          // N*384
    int*   counts  = (int*)(v_agg + (size_t)N_NODES * F3); // N
    int*   row_start = counts + N_NODES;                   // N+1
    int*   cursor  = row_start + N_NODES + 1;              // N
    int*   edge_ids = cursor + N_NODES;                    // E
    int*   chunk_sum = edge_ids + E_EDGES;                 // 128
    int*   chunk_off = chunk_sum + 128;                    // 128
    unsigned short* W1s = (unsigned short*)(chunk_off + 128);  // 8*4*64*8
    unsigned short* W2s = W1s + 8 * 4 * 64 * 8;                // 24*4*64*8

    hipMemsetAsync(counts, 0, sizeof(int) * N_NODES, stream);

    w_swizzle_kernel<<<32, 256, 0, stream>>>(W1, W2, W1s, W2s);
    node_mlp_mfma<<<(N_NODES + 63) / 64, 256, 0, stream>>>(s, b1, b2, W1s, W2s, h);

    hist_kernel<<<(E_EDGES + 255) / 256, 256, 0, stream>>>(i_index, counts);
    scan_p1<<<NCHUNK, 256, 0, stream>>>(counts, row_start, chunk_sum);
    scan_p2<<<1, 128, 0, stream>>>(chunk_sum, chunk_off);
    scan_p3<<<NCHUNK, 256, 0, stream>>>(row_start, chunk_off, cursor);
    scatter_kernel<<<(E_EDGES + 255) / 256, 256, 0, stream>>>(i_index, cursor, edge_ids);

    agg_kernel<<<N_NODES, 128, 0, stream>>>(s, v, rbf, dir, j_index, Wr, br, h,
                                            row_start, edge_ids, s_agg, v_agg);

    update_kernel<<<N_NODES / T_C, 128, 0, stream>>>(s_agg, v_agg, WU, bU, WV, bV,
                                                     M1, bm1, M2, bm2, out_s, out_v);
}